// Round 9
// baseline (176.400 us; speedup 1.0000x reference)
//
#include <hip/hip_runtime.h>

// Kill FMA contraction globally: the MASK must match numpy/XLA's separate
// mul+add rounding bit-for-bit, or borderline mask bits flip and the whole
// compaction permutation shifts. Fast paths use explicit fmaf()/rcp-mul.
#pragma clang fp contract(off)

namespace {

constexpr int S = 64;
// linspace(0,1,64): t_i = i * fl(1/63). fl(63*fl(1/63)) == 1.0f exactly.
constexpr float DELTA = 1.0f / 63.0f;

constexpr int RPB = 16;                   // rays per staging block
constexpr int TPR = 256 / RPB;            // threads per ray (16)
constexpr int SPT = S / TPR;              // samples per thread (4)
constexpr int Q = RPB * S;                // 1024 samples per block
constexpr int LQ = Q + 16;                // scalar-array LDS slot (mod-4 shift pad)
constexpr int SB = 4 * LQ;                // samples region base
constexpr int LDSF = SB + 3 * Q + 16;     // 7248 floats = 29.0 KB

// Native clang vector type: __builtin_nontemporal_store requires a pointer to
// scalar or native vector (HIP_vector_type float4 is rejected).
typedef float f32x4 __attribute__((ext_vector_type(4)));

// Non-temporal store helpers: bypass L2/LLC allocation for the 470 MB write
// flood (no read-for-ownership, no pollution of the ~14 MB read set).
__device__ __forceinline__ void nts(float v, float* p) {
  __builtin_nontemporal_store(v, p);
}
__device__ __forceinline__ void nts4(const float* lds, float* p) {
  f32x4 v = *reinterpret_cast<const f32x4*>(lds);
  __builtin_nontemporal_store(v, reinterpret_cast<f32x4*>(p));
}

__device__ __forceinline__ void ray_nearfar(
    float ox, float oy, float oz,
    float dx, float dy, float dz,
    float R, float& nr, float& fr) {
  float ix = 1.0f / ((dx == 0.0f) ? 1e-6f : dx);
  float iy = 1.0f / ((dy == 0.0f) ? 1e-6f : dy);
  float iz = 1.0f / ((dz == 0.0f) ? 1e-6f : dz);
  float mR = -R;
  float ax = (mR - ox) * ix, bx = (R - ox) * ix;
  float ay = (mR - oy) * iy, by = (R - oy) * iy;
  float az = (mR - oz) * iz, bz = (R - oz) * iz;
  nr = fmaxf(fmaxf(fminf(ax, bx), fminf(ay, by)), fminf(az, bz));
  fr = fminf(fminf(fmaxf(ax, bx), fmaxf(ay, by)), fmaxf(az, bz));
}

// Kernel A: one thread per ray: near/f + 64-bit validity mask -> rayinfo.
// Fast mask: rcp-mul + fma q; only |q-1| < 6e-5 (error bound ~8e-7, 75x
// margin) re-runs the exact IEEE sequence. sqrt-free: RN(sqrt(q)) <= 1.0
// <=> q <= 1+2^-23. (Validated in R7: num_valid exact.)
__global__ __launch_bounds__(256) void k_count(
    const float* __restrict__ ro, const float* __restrict__ rd,
    const float* __restrict__ radii,
    float4* __restrict__ rayinfo,
    int* __restrict__ L, int* __restrict__ blockSums, int N) {
  int r = blockIdx.x * 256 + threadIdx.x;
  int cnt = 0;
  const float QLIM = __uint_as_float(0x3F800001u);  // 1 + 2^-23
  if (r < N) {
    float R = radii[0];
    float invR = 1.0f / R;
    float ox = ro[3 * r], oy = ro[3 * r + 1], oz = ro[3 * r + 2];
    float dx = rd[3 * r], dy = rd[3 * r + 1], dz = rd[3 * r + 2];
    float nr, fr;
    ray_nearfar(ox, oy, oz, dx, dy, dz, R, nr, fr);
    float f = fr - nr;
    unsigned lo = 0, hi = 0;
    for (int s = 0; s < S; ++s) {
      float dep = nr + f * ((float)s * DELTA);   // exact (contract off)
      float sxf = fmaf(dx, dep, ox) * invR;      // fast path
      float syf = fmaf(dy, dep, oy) * invR;
      float szf = fmaf(dz, dep, oz) * invR;
      float qf = fmaf(sxf, sxf, fmaf(syf, syf, szf * szf));
      unsigned bit;
      if (__builtin_expect(fabsf(qf - 1.0f) > 6e-5f, 1)) {
        bit = (qf <= 1.0f) ? 1u : 0u;
      } else {                                    // exact IEEE replication
        float sx = (ox + dx * dep) / R;
        float sy = (oy + dy * dep) / R;
        float sz = (oz + dz * dep) / R;
        float q = (sx * sx + sy * sy) + sz * sz;
        bit = (q <= QLIM) ? 1u : 0u;
      }
      if (s < 32) lo |= bit << s; else hi |= bit << (s - 32);
      cnt += (int)bit;
    }
    rayinfo[r] = make_float4(nr, f, __uint_as_float(lo), __uint_as_float(hi));
  }
  __shared__ int sm[256];
  sm[threadIdx.x] = cnt;
  __syncthreads();
  for (int off = 1; off < 256; off <<= 1) {
    int t = (threadIdx.x >= off) ? sm[threadIdx.x - off] : 0;
    __syncthreads();
    sm[threadIdx.x] += t;
    __syncthreads();
  }
  if (r < N) L[r] = sm[threadIdx.x] - cnt;  // exclusive within block
  if (threadIdx.x == 255) blockSums[blockIdx.x] = sm[255];
}

// Kernel B: single block scans the (<=1024) block sums.
__global__ __launch_bounds__(1024) void k_scan(
    const int* __restrict__ blockSums, int* __restrict__ blockOff,
    int* __restrict__ total, float* __restrict__ out_nv, int nb) {
  __shared__ int sm[1024];
  int x = (threadIdx.x < nb) ? blockSums[threadIdx.x] : 0;
  sm[threadIdx.x] = x;
  __syncthreads();
  for (int off = 1; off < 1024; off <<= 1) {
    int t = (threadIdx.x >= off) ? sm[threadIdx.x - off] : 0;
    __syncthreads();
    sm[threadIdx.x] += t;
    __syncthreads();
  }
  if (threadIdx.x < nb) blockOff[threadIdx.x] = sm[threadIdx.x] - x;
  if (threadIdx.x == 1023) {
    *total = sm[1023];
    out_nv[0] = (float)sm[1023];
  }
}

// Kernel C: 16 rays per block. Block-local stable partition into LDS laid out
// congruent (mod 4 floats) with each run's global destination; write phase
// streams aligned float4 runs with NON-TEMPORAL stores.
__global__ __launch_bounds__(256) void k_stage(
    const float* __restrict__ ro, const float* __restrict__ rd,
    const float* __restrict__ radii,
    const float4* __restrict__ rayinfo,
    const int* __restrict__ L, const int* __restrict__ blockOff,
    const int* __restrict__ total,
    float* __restrict__ out, int N) {
  __shared__ __align__(16) float buf[LDSF];
  int nwg = gridDim.x;                 // 16384, divisible by 8
  int chunk = nwg >> 3;
  int hw = blockIdx.x;
  int bid = (hw & 7) * chunk + (hw >> 3);   // XCD-chunked swizzle
  int r0 = bid * RPB;
  int tid = threadIdx.x;
  int nv = *total;
  int V0 = L[r0] + blockOff[r0 >> 8];
  int rB = r0 + RPB;
  int VB = (rB >= N) ? nv : (L[rB] + blockOff[rB >> 8]);
  int cV = VB - V0;                    // valid samples in this block
  int cT = Q - cV;
  int TV = r0 * S - V0;                // invalid samples before this block
  size_t tail0 = (size_t)nv + (size_t)TV;

  // LDS run bases, congruent mod 4 with global dests.
  int sv = V0 & 3;
  int st = ((sv + cV + 3) & ~3) + (int)(tail0 & 3);
  int svS = (3 * V0) & 3;
  int stS = ((svS + 3 * cV + 3) & ~3) + (int)((3 * tail0) & 3);

  // ---- compute + local stable partition into LDS ----
  int r = r0 + (tid >> 4);             // 16 threads per ray
  float R = radii[0];
  float invR = 1.0f / R;               // once; per-sample values use mul
  float4 info = rayinfo[r];
  float nr = info.x, f = info.y;
  unsigned long long msk =
      ((unsigned long long)__float_as_uint(info.w) << 32) |
      (unsigned long long)__float_as_uint(info.z);
  float ox = ro[3 * r], oy = ro[3 * r + 1], oz = ro[3 * r + 2];
  float dx = rd[3 * r], dy = rd[3 * r + 1], dz = rd[3 * r + 2];
  int Vr = L[r] + blockOff[r >> 8];
  float fridx = (float)r;
  int idxvB = Vr - V0;                 // block-local valid base for this ray
  int idxtB = (r * S - Vr) - TV;       // block-local tail base for this ray
  #pragma unroll
  for (int j = 0; j < SPT; ++j) {
    int s = (tid & (TPR - 1)) + TPR * j;  // ray's lanes -> consecutive dests
    bool bit = (msk >> s) & 1ull;
    int below = __popcll(msk & ((1ull << s) - 1ull));
    float dep = fmaf(f, (float)s * DELTA, nr);
    float sx = fmaf(dx, dep, ox) * invR;
    float sy = fmaf(dy, dep, oy) * invR;
    float sz = fmaf(dz, dep, oz) * invR;
    float prev = fmaf(f, (float)(s - 1) * DELTA, nr);
    float del = s ? (dep - prev) : 0.0f;
    int i1 = bit ? (idxvB + below) : (idxtB + (s - below));
    int b0 = (bit ? sv : st) + i1;
    buf[b0] = fridx;                   // ridx      (slot 0)
    buf[b0 + LQ] = dep;                // depth     (slot 1)
    buf[b0 + 2 * LQ] = del;            // deltas    (slot 2)
    buf[b0 + 3 * LQ] = (bit && below == 0) ? 1.0f : 0.0f;  // boundary (slot 3)
    int b1 = SB + (bit ? svS : stS) + 3 * i1;
    buf[b1] = sx; buf[b1 + 1] = sy; buf[b1 + 2] = sz;
  }
  __syncthreads();

  // ---- streaming write phase (non-temporal) ----
  size_t M = (size_t)N * S;
  // global bases of the 4 scalar arrays: ridx 0, depth 4M, deltas 5M, bnd 6M
  const size_t A1 = 4 * M, A2 = 5 * M, A3 = 6 * M;

  // fused scalar runs (valid then tail)
  {
    int a0 = (-V0) & 3; if (a0 > cV) a0 = cV;
    int body = cV - a0, n4 = body >> 2, rem = body & 3;
    int l0 = sv + a0;                  // multiple of 4
    size_t g = (size_t)V0 + a0;
    for (int c = tid; c < n4; c += 256) {
      int l = l0 + 4 * c; size_t gg = g + 4 * (size_t)c;
      nts4(&buf[l],          out + gg);
      nts4(&buf[l + LQ],     out + A1 + gg);
      nts4(&buf[l + 2 * LQ], out + A2 + gg);
      nts4(&buf[l + 3 * LQ], out + A3 + gg);
    }
    if (tid < a0) {
      size_t gg = (size_t)V0 + tid; int l = sv + tid;
      nts(buf[l], out + gg);          nts(buf[l + LQ], out + A1 + gg);
      nts(buf[l + 2 * LQ], out + A2 + gg); nts(buf[l + 3 * LQ], out + A3 + gg);
    }
    if (tid < rem) {
      int e = a0 + 4 * n4 + tid;
      size_t gg = (size_t)V0 + e; int l = sv + e;
      nts(buf[l], out + gg);          nts(buf[l + LQ], out + A1 + gg);
      nts(buf[l + 2 * LQ], out + A2 + gg); nts(buf[l + 3 * LQ], out + A3 + gg);
    }
  }
  {
    int a0 = (int)((-tail0) & 3); if (a0 > cT) a0 = cT;
    int body = cT - a0, n4 = body >> 2, rem = body & 3;
    int l0 = st + a0;
    size_t g = tail0 + a0;
    for (int c = tid; c < n4; c += 256) {
      int l = l0 + 4 * c; size_t gg = g + 4 * (size_t)c;
      nts4(&buf[l],          out + gg);
      nts4(&buf[l + LQ],     out + A1 + gg);
      nts4(&buf[l + 2 * LQ], out + A2 + gg);
      nts4(&buf[l + 3 * LQ], out + A3 + gg);
    }
    if (tid < a0) {
      size_t gg = tail0 + tid; int l = st + tid;
      nts(buf[l], out + gg);          nts(buf[l + LQ], out + A1 + gg);
      nts(buf[l + 2 * LQ], out + A2 + gg); nts(buf[l + 3 * LQ], out + A3 + gg);
    }
    if (tid < rem) {
      int e = a0 + 4 * n4 + tid;
      size_t gg = tail0 + e; int l = st + e;
      nts(buf[l], out + gg);          nts(buf[l + LQ], out + A1 + gg);
      nts(buf[l + 2 * LQ], out + A2 + gg); nts(buf[l + 3 * LQ], out + A3 + gg);
    }
  }
  // samples runs (scale 3)
  {
    size_t g0 = M + 3 * (size_t)V0; int cnt = 3 * cV;
    int a0 = (int)((-g0) & 3); if (a0 > cnt) a0 = cnt;
    int body = cnt - a0, n4 = body >> 2, rem = body & 3;
    int l0 = SB + svS + a0;
    for (int c = tid; c < n4; c += 256)
      nts4(&buf[l0 + 4 * c], out + g0 + a0 + 4 * (size_t)c);
    if (tid < a0) nts(buf[SB + svS + tid], out + g0 + tid);
    if (tid < rem) { int e = a0 + 4 * n4 + tid; nts(buf[SB + svS + e], out + g0 + e); }
  }
  {
    size_t g0 = M + 3 * tail0; int cnt = 3 * cT;
    int a0 = (int)((-g0) & 3); if (a0 > cnt) a0 = cnt;
    int body = cnt - a0, n4 = body >> 2, rem = body & 3;
    int l0 = SB + stS + a0;
    for (int c = tid; c < n4; c += 256)
      nts4(&buf[l0 + 4 * c], out + g0 + a0 + 4 * (size_t)c);
    if (tid < a0) nts(buf[SB + stS + tid], out + g0 + tid);
    if (tid < rem) { int e = a0 + 4 * n4 + tid; nts(buf[SB + stS + e], out + g0 + e); }
  }
}

}  // namespace

extern "C" void kernel_launch(void* const* d_in, const int* in_sizes, int n_in,
                              void* d_out, int out_size, void* d_ws, size_t ws_size,
                              hipStream_t stream) {
  const float* ro = (const float*)d_in[0];
  const float* rd = (const float*)d_in[1];
  const float* radii = (const float*)d_in[2];
  int N = in_sizes[0] / 3;           // 262144
  int M = N * S;                     // 16777216
  int nbA = (N + 255) / 256;         // 1024

  float4* rayinfo = (float4*)d_ws;             // N float4 (16B aligned)
  int* wsI = (int*)(rayinfo + N);
  int* L = wsI;                      // N ints
  int* blockSums = wsI + N;          // nbA ints
  int* blockOff = blockSums + nbA;   // nbA ints
  int* total = blockOff + nbA;       // 1 int

  float* out = (float*)d_out;
  float* out_nv = out + (size_t)7 * (size_t)M;  // num_valid slot

  k_count<<<nbA, 256, 0, stream>>>(ro, rd, radii, rayinfo, L, blockSums, N);
  k_scan<<<1, 1024, 0, stream>>>(blockSums, blockOff, total, out_nv, nbA);
  k_stage<<<N / RPB, 256, 0, stream>>>(ro, rd, radii, rayinfo, L, blockOff,
                                       total, out, N);
}

// Round 10
// 138.943 us; speedup vs baseline: 1.2696x; 1.2696x over previous
//
#include <hip/hip_runtime.h>

// Kill FMA contraction globally: the MASK must match numpy/XLA's separate
// mul+add rounding bit-for-bit, or borderline mask bits flip and the whole
// compaction permutation shifts. Fast paths use explicit fmaf()/rcp-mul.
#pragma clang fp contract(off)

namespace {

constexpr int S = 64;
// linspace(0,1,64): t_i = i * fl(1/63). fl(63*fl(1/63)) == 1.0f exactly.
constexpr float DELTA = 1.0f / 63.0f;

constexpr int RPB = 16;                   // rays per staging block
constexpr int TPR = 256 / RPB;            // threads per ray (16)
constexpr int SPT = S / TPR;              // samples per thread (4)
constexpr int Q = RPB * S;                // 1024 samples per block
constexpr int LQ = Q + 16;                // scalar-array LDS slot (mod-4 shift pad)
constexpr int SB = 4 * LQ;                // samples region base
constexpr int LDSF = SB + 3 * Q + 16;     // 7248 floats = 29.0 KB

__device__ __forceinline__ void ray_nearfar(
    float ox, float oy, float oz,
    float dx, float dy, float dz,
    float R, float& nr, float& fr) {
  float ix = 1.0f / ((dx == 0.0f) ? 1e-6f : dx);
  float iy = 1.0f / ((dy == 0.0f) ? 1e-6f : dy);
  float iz = 1.0f / ((dz == 0.0f) ? 1e-6f : dz);
  float mR = -R;
  float ax = (mR - ox) * ix, bx = (R - ox) * ix;
  float ay = (mR - oy) * iy, by = (R - oy) * iy;
  float az = (mR - oz) * iz, bz = (R - oz) * iz;
  nr = fmaxf(fmaxf(fminf(ax, bx), fminf(ay, by)), fminf(az, bz));
  fr = fminf(fminf(fmaxf(ax, bx), fmaxf(ay, by)), fmaxf(az, bz));
}

// Kernel A: one thread per ray: near/f + 64-bit validity mask -> rayinfo.
// Fast mask: rcp-mul + fma q; only |q-1| < 6e-5 (error bound ~8e-7, 75x
// margin) re-runs the exact IEEE sequence. sqrt-free: RN(sqrt(q)) <= 1.0
// <=> q <= 1+2^-23. (Validated R7/R9: num_valid exact.)
__global__ __launch_bounds__(256) void k_count(
    const float* __restrict__ ro, const float* __restrict__ rd,
    const float* __restrict__ radii,
    float4* __restrict__ rayinfo,
    int* __restrict__ L, int* __restrict__ blockSums, int N) {
  int r = blockIdx.x * 256 + threadIdx.x;
  int cnt = 0;
  const float QLIM = __uint_as_float(0x3F800001u);  // 1 + 2^-23
  if (r < N) {
    float R = radii[0];
    float invR = 1.0f / R;
    float ox = ro[3 * r], oy = ro[3 * r + 1], oz = ro[3 * r + 2];
    float dx = rd[3 * r], dy = rd[3 * r + 1], dz = rd[3 * r + 2];
    float nr, fr;
    ray_nearfar(ox, oy, oz, dx, dy, dz, R, nr, fr);
    float f = fr - nr;
    unsigned lo = 0, hi = 0;
    for (int s = 0; s < S; ++s) {
      float dep = nr + f * ((float)s * DELTA);   // exact (contract off)
      float sxf = fmaf(dx, dep, ox) * invR;      // fast path
      float syf = fmaf(dy, dep, oy) * invR;
      float szf = fmaf(dz, dep, oz) * invR;
      float qf = fmaf(sxf, sxf, fmaf(syf, syf, szf * szf));
      unsigned bit;
      if (__builtin_expect(fabsf(qf - 1.0f) > 6e-5f, 1)) {
        bit = (qf <= 1.0f) ? 1u : 0u;
      } else {                                    // exact IEEE replication
        float sx = (ox + dx * dep) / R;
        float sy = (oy + dy * dep) / R;
        float sz = (oz + dz * dep) / R;
        float q = (sx * sx + sy * sy) + sz * sz;
        bit = (q <= QLIM) ? 1u : 0u;
      }
      if (s < 32) lo |= bit << s; else hi |= bit << (s - 32);
      cnt += (int)bit;
    }
    rayinfo[r] = make_float4(nr, f, __uint_as_float(lo), __uint_as_float(hi));
  }
  __shared__ int sm[256];
  sm[threadIdx.x] = cnt;
  __syncthreads();
  for (int off = 1; off < 256; off <<= 1) {
    int t = (threadIdx.x >= off) ? sm[threadIdx.x - off] : 0;
    __syncthreads();
    sm[threadIdx.x] += t;
    __syncthreads();
  }
  if (r < N) L[r] = sm[threadIdx.x] - cnt;  // exclusive within block
  if (threadIdx.x == 255) blockSums[blockIdx.x] = sm[255];
}

// Kernel B: single block scans the (<=1024) block sums.
__global__ __launch_bounds__(1024) void k_scan(
    const int* __restrict__ blockSums, int* __restrict__ blockOff,
    int* __restrict__ total, float* __restrict__ out_nv, int nb) {
  __shared__ int sm[1024];
  int x = (threadIdx.x < nb) ? blockSums[threadIdx.x] : 0;
  sm[threadIdx.x] = x;
  __syncthreads();
  for (int off = 1; off < 1024; off <<= 1) {
    int t = (threadIdx.x >= off) ? sm[threadIdx.x - off] : 0;
    __syncthreads();
    sm[threadIdx.x] += t;
    __syncthreads();
  }
  if (threadIdx.x < nb) blockOff[threadIdx.x] = sm[threadIdx.x] - x;
  if (threadIdx.x == 1023) {
    *total = sm[1023];
    out_nv[0] = (float)sm[1023];
  }
}

// Kernel C: 16 rays per block. Block-local stable partition into LDS laid out
// congruent (mod 4 floats) with each run's global destination. Write phase:
// each WAVE owns 2-4 runs and streams them SEQUENTIALLY (batched per-stream
// bursts -> DRAM row locality), instead of round-robining 10 streams.
__global__ __launch_bounds__(256) void k_stage(
    const float* __restrict__ ro, const float* __restrict__ rd,
    const float* __restrict__ radii,
    const float4* __restrict__ rayinfo,
    const int* __restrict__ L, const int* __restrict__ blockOff,
    const int* __restrict__ total,
    float* __restrict__ out, int N) {
  __shared__ __align__(16) float buf[LDSF];
  int nwg = gridDim.x;                 // 16384, divisible by 8
  int chunk = nwg >> 3;
  int hw = blockIdx.x;
  int bid = (hw & 7) * chunk + (hw >> 3);   // XCD-chunked swizzle
  int r0 = bid * RPB;
  int tid = threadIdx.x;
  int nv = *total;
  int V0 = L[r0] + blockOff[r0 >> 8];
  int rB = r0 + RPB;
  int VB = (rB >= N) ? nv : (L[rB] + blockOff[rB >> 8]);
  int cV = VB - V0;                    // valid samples in this block
  int cT = Q - cV;
  int TV = r0 * S - V0;                // invalid samples before this block
  size_t tail0 = (size_t)nv + (size_t)TV;

  // LDS run bases, congruent mod 4 with global dests.
  int sv = V0 & 3;
  int st = ((sv + cV + 3) & ~3) + (int)(tail0 & 3);
  int svS = (3 * V0) & 3;
  int stS = ((svS + 3 * cV + 3) & ~3) + (int)((3 * tail0) & 3);

  // ---- compute + local stable partition into LDS ----
  int r = r0 + (tid >> 4);             // 16 threads per ray
  float R = radii[0];
  float invR = 1.0f / R;               // once; per-sample values use mul
  float4 info = rayinfo[r];
  float nr = info.x, f = info.y;
  unsigned long long msk =
      ((unsigned long long)__float_as_uint(info.w) << 32) |
      (unsigned long long)__float_as_uint(info.z);
  float ox = ro[3 * r], oy = ro[3 * r + 1], oz = ro[3 * r + 2];
  float dx = rd[3 * r], dy = rd[3 * r + 1], dz = rd[3 * r + 2];
  int Vr = L[r] + blockOff[r >> 8];
  float fridx = (float)r;
  int idxvB = Vr - V0;                 // block-local valid base for this ray
  int idxtB = (r * S - Vr) - TV;       // block-local tail base for this ray
  #pragma unroll
  for (int j = 0; j < SPT; ++j) {
    int s = (tid & (TPR - 1)) + TPR * j;  // ray's lanes -> consecutive dests
    bool bit = (msk >> s) & 1ull;
    int below = __popcll(msk & ((1ull << s) - 1ull));
    float dep = fmaf(f, (float)s * DELTA, nr);
    float sx = fmaf(dx, dep, ox) * invR;
    float sy = fmaf(dy, dep, oy) * invR;
    float sz = fmaf(dz, dep, oz) * invR;
    float prev = fmaf(f, (float)(s - 1) * DELTA, nr);
    float del = s ? (dep - prev) : 0.0f;
    int i1 = bit ? (idxvB + below) : (idxtB + (s - below));
    int b0 = (bit ? sv : st) + i1;
    buf[b0] = fridx;                   // ridx      (slot 0)
    buf[b0 + LQ] = dep;                // depth     (slot 1)
    buf[b0 + 2 * LQ] = del;            // deltas    (slot 2)
    buf[b0 + 3 * LQ] = (bit && below == 0) ? 1.0f : 0.0f;  // boundary (slot 3)
    int b1 = SB + (bit ? svS : stS) + 3 * i1;
    buf[b1] = sx; buf[b1 + 1] = sy; buf[b1 + 2] = sz;
  }
  __syncthreads();

  // ---- write phase: wave-owned sequential runs ----
  size_t M = (size_t)N * S;
  const size_t A1 = 4 * M, A2 = 5 * M, A3 = 6 * M;
  int w = tid >> 6, lane = tid & 63;

  // single-wave run writer: head fringe, float4 body, tail fringe
  auto wrw = [&](int lds0, size_t g0, int cnt) {
    int a0 = (int)((4 - (g0 & 3)) & 3);
    if (a0 > cnt) a0 = cnt;
    int body = cnt - a0, n4 = body >> 2, rem = body & 3;
    if (lane < a0) out[g0 + lane] = buf[lds0 + lane];
    int l0 = lds0 + a0;                // multiple of 4 by congruence
    for (int c = lane; c < n4; c += 64)
      *(float4*)(out + g0 + a0 + 4 * (size_t)c) = *(const float4*)&buf[l0 + 4 * c];
    if (lane < rem) {
      int e = a0 + 4 * n4 + lane;
      out[g0 + e] = buf[lds0 + e];
    }
  };

  // samples-valid run split in half between waves 0 and 1 (balance)
  int s0l = SB + svS;
  size_t g0s = M + 3 * (size_t)V0;
  int cnts = 3 * cV;
  int a0s = (int)((4 - (g0s & 3)) & 3);
  if (a0s > cnts) a0s = cnts;
  int hsplit = a0s + 4 * (((cnts - a0s) >> 2) >> 1);

  if (w == 0) {
    wrw(s0l, g0s, hsplit);
  } else if (w == 1) {
    wrw(s0l + hsplit, g0s + hsplit, cnts - hsplit);
    wrw(SB + stS, M + 3 * tail0, 3 * cT);
  } else if (w == 2) {
    wrw(sv, (size_t)V0, cV);                 // ridx-v
    wrw(sv + LQ, A1 + (size_t)V0, cV);       // depth-v
    wrw(st, tail0, cT);                      // ridx-t
    wrw(st + LQ, A1 + tail0, cT);            // depth-t
  } else {
    wrw(sv + 2 * LQ, A2 + (size_t)V0, cV);   // deltas-v
    wrw(sv + 3 * LQ, A3 + (size_t)V0, cV);   // bnd-v
    wrw(st + 2 * LQ, A2 + tail0, cT);        // deltas-t
    wrw(st + 3 * LQ, A3 + tail0, cT);        // bnd-t
  }
}

}  // namespace

extern "C" void kernel_launch(void* const* d_in, const int* in_sizes, int n_in,
                              void* d_out, int out_size, void* d_ws, size_t ws_size,
                              hipStream_t stream) {
  const float* ro = (const float*)d_in[0];
  const float* rd = (const float*)d_in[1];
  const float* radii = (const float*)d_in[2];
  int N = in_sizes[0] / 3;           // 262144
  int M = N * S;                     // 16777216
  int nbA = (N + 255) / 256;         // 1024

  float4* rayinfo = (float4*)d_ws;             // N float4 (16B aligned)
  int* wsI = (int*)(rayinfo + N);
  int* L = wsI;                      // N ints
  int* blockSums = wsI + N;          // nbA ints
  int* blockOff = blockSums + nbA;   // nbA ints
  int* total = blockOff + nbA;       // 1 int

  float* out = (float*)d_out;
  float* out_nv = out + (size_t)7 * (size_t)M;  // num_valid slot

  k_count<<<nbA, 256, 0, stream>>>(ro, rd, radii, rayinfo, L, blockSums, N);
  k_scan<<<1, 1024, 0, stream>>>(blockSums, blockOff, total, out_nv, nbA);
  k_stage<<<N / RPB, 256, 0, stream>>>(ro, rd, radii, rayinfo, L, blockOff,
                                       total, out, N);
}

// Round 11
// 137.728 us; speedup vs baseline: 1.2808x; 1.0088x over previous
//
#include <hip/hip_runtime.h>

// Kill FMA contraction globally: the MASK must match numpy/XLA's separate
// mul+add rounding bit-for-bit, or borderline mask bits flip and the whole
// compaction permutation shifts. Fast paths use explicit fmaf()/rcp-mul.
#pragma clang fp contract(off)

namespace {

constexpr int S = 64;
// linspace(0,1,64): t_i = i * fl(1/63). fl(63*fl(1/63)) == 1.0f exactly.
constexpr float DELTA = 1.0f / 63.0f;

constexpr int RPB = 32;                   // rays per staging block
constexpr int THREADS = 512;              // 8 waves
constexpr int TPR = THREADS / RPB;        // threads per ray (16)
constexpr int SPT = S / TPR;              // samples per thread (4)
constexpr int Q = RPB * S;                // 2048 samples per block
constexpr int LQ = Q + 16;                // scalar-array LDS slot (mod-4 shift pad)
constexpr int SB = 4 * LQ;                // samples region base
constexpr int LDSF = SB + 3 * Q + 16;     // 14416 floats = 57.7 KB (2 blocks/CU)

__device__ __forceinline__ void ray_nearfar(
    float ox, float oy, float oz,
    float dx, float dy, float dz,
    float R, float& nr, float& fr) {
  float ix = 1.0f / ((dx == 0.0f) ? 1e-6f : dx);
  float iy = 1.0f / ((dy == 0.0f) ? 1e-6f : dy);
  float iz = 1.0f / ((dz == 0.0f) ? 1e-6f : dz);
  float mR = -R;
  float ax = (mR - ox) * ix, bx = (R - ox) * ix;
  float ay = (mR - oy) * iy, by = (R - oy) * iy;
  float az = (mR - oz) * iz, bz = (R - oz) * iz;
  nr = fmaxf(fmaxf(fminf(ax, bx), fminf(ay, by)), fminf(az, bz));
  fr = fminf(fminf(fmaxf(ax, bx), fmaxf(ay, by)), fmaxf(az, bz));
}

// Kernel A: one thread per ray: near/f + 64-bit validity mask -> rayinfo.
// Fast mask: rcp-mul + fma q; only |q-1| < 6e-5 (error bound ~8e-7, 75x
// margin) re-runs the exact IEEE sequence. sqrt-free: RN(sqrt(q)) <= 1.0
// <=> q <= 1+2^-23. (Validated R7/R9/R10: num_valid exact.)
__global__ __launch_bounds__(256) void k_count(
    const float* __restrict__ ro, const float* __restrict__ rd,
    const float* __restrict__ radii,
    float4* __restrict__ rayinfo,
    int* __restrict__ L, int* __restrict__ blockSums, int N) {
  int r = blockIdx.x * 256 + threadIdx.x;
  int cnt = 0;
  const float QLIM = __uint_as_float(0x3F800001u);  // 1 + 2^-23
  if (r < N) {
    float R = radii[0];
    float invR = 1.0f / R;
    float ox = ro[3 * r], oy = ro[3 * r + 1], oz = ro[3 * r + 2];
    float dx = rd[3 * r], dy = rd[3 * r + 1], dz = rd[3 * r + 2];
    float nr, fr;
    ray_nearfar(ox, oy, oz, dx, dy, dz, R, nr, fr);
    float f = fr - nr;
    unsigned lo = 0, hi = 0;
    for (int s = 0; s < S; ++s) {
      float dep = nr + f * ((float)s * DELTA);   // exact (contract off)
      float sxf = fmaf(dx, dep, ox) * invR;      // fast path
      float syf = fmaf(dy, dep, oy) * invR;
      float szf = fmaf(dz, dep, oz) * invR;
      float qf = fmaf(sxf, sxf, fmaf(syf, syf, szf * szf));
      unsigned bit;
      if (__builtin_expect(fabsf(qf - 1.0f) > 6e-5f, 1)) {
        bit = (qf <= 1.0f) ? 1u : 0u;
      } else {                                    // exact IEEE replication
        float sx = (ox + dx * dep) / R;
        float sy = (oy + dy * dep) / R;
        float sz = (oz + dz * dep) / R;
        float q = (sx * sx + sy * sy) + sz * sz;
        bit = (q <= QLIM) ? 1u : 0u;
      }
      if (s < 32) lo |= bit << s; else hi |= bit << (s - 32);
      cnt += (int)bit;
    }
    rayinfo[r] = make_float4(nr, f, __uint_as_float(lo), __uint_as_float(hi));
  }
  __shared__ int sm[256];
  sm[threadIdx.x] = cnt;
  __syncthreads();
  for (int off = 1; off < 256; off <<= 1) {
    int t = (threadIdx.x >= off) ? sm[threadIdx.x - off] : 0;
    __syncthreads();
    sm[threadIdx.x] += t;
    __syncthreads();
  }
  if (r < N) L[r] = sm[threadIdx.x] - cnt;  // exclusive within block
  if (threadIdx.x == 255) blockSums[blockIdx.x] = sm[255];
}

// Kernel B: single block scans the (<=1024) block sums.
__global__ __launch_bounds__(1024) void k_scan(
    const int* __restrict__ blockSums, int* __restrict__ blockOff,
    int* __restrict__ total, float* __restrict__ out_nv, int nb) {
  __shared__ int sm[1024];
  int x = (threadIdx.x < nb) ? blockSums[threadIdx.x] : 0;
  sm[threadIdx.x] = x;
  __syncthreads();
  for (int off = 1; off < 1024; off <<= 1) {
    int t = (threadIdx.x >= off) ? sm[threadIdx.x - off] : 0;
    __syncthreads();
    sm[threadIdx.x] += t;
    __syncthreads();
  }
  if (threadIdx.x < nb) blockOff[threadIdx.x] = sm[threadIdx.x] - x;
  if (threadIdx.x == 1023) {
    *total = sm[1023];
    out_nv[0] = (float)sm[1023];
  }
}

// Kernel C: 32 rays / 512 threads per block. Block-local stable partition into
// LDS congruent (mod 4 floats) with each run's global destination; write phase
// streams aligned float4 runs (fused 4-array scalar loop, R5 structure).
// Doubled run length (6.6 KB scalar / 20 KB samples) and halved block count
// vs R5 to test DRAM/L2 write-window locality.
__global__ __launch_bounds__(THREADS) void k_stage(
    const float* __restrict__ ro, const float* __restrict__ rd,
    const float* __restrict__ radii,
    const float4* __restrict__ rayinfo,
    const int* __restrict__ L, const int* __restrict__ blockOff,
    const int* __restrict__ total,
    float* __restrict__ out, int N) {
  __shared__ __align__(16) float buf[LDSF];
  int nwg = gridDim.x;                 // 8192, divisible by 8
  int chunk = nwg >> 3;
  int hw = blockIdx.x;
  int bid = (hw & 7) * chunk + (hw >> 3);   // XCD-chunked swizzle
  int r0 = bid * RPB;
  int tid = threadIdx.x;
  int nv = *total;
  int V0 = L[r0] + blockOff[r0 >> 8];
  int rB = r0 + RPB;
  int VB = (rB >= N) ? nv : (L[rB] + blockOff[rB >> 8]);
  int cV = VB - V0;                    // valid samples in this block
  int cT = Q - cV;
  int TV = r0 * S - V0;                // invalid samples before this block
  size_t tail0 = (size_t)nv + (size_t)TV;

  // LDS run bases, congruent mod 4 with global dests.
  int sv = V0 & 3;
  int st = ((sv + cV + 3) & ~3) + (int)(tail0 & 3);
  int svS = (3 * V0) & 3;
  int stS = ((svS + 3 * cV + 3) & ~3) + (int)((3 * tail0) & 3);

  // ---- compute + local stable partition into LDS ----
  int r = r0 + (tid >> 4);             // 16 threads per ray
  float R = radii[0];
  float invR = 1.0f / R;               // once; per-sample values use mul
  float4 info = rayinfo[r];
  float nr = info.x, f = info.y;
  unsigned long long msk =
      ((unsigned long long)__float_as_uint(info.w) << 32) |
      (unsigned long long)__float_as_uint(info.z);
  float ox = ro[3 * r], oy = ro[3 * r + 1], oz = ro[3 * r + 2];
  float dx = rd[3 * r], dy = rd[3 * r + 1], dz = rd[3 * r + 2];
  int Vr = L[r] + blockOff[r >> 8];
  float fridx = (float)r;
  int idxvB = Vr - V0;                 // block-local valid base for this ray
  int idxtB = (r * S - Vr) - TV;       // block-local tail base for this ray
  #pragma unroll
  for (int j = 0; j < SPT; ++j) {
    int s = (tid & (TPR - 1)) + TPR * j;  // ray's lanes -> consecutive dests
    bool bit = (msk >> s) & 1ull;
    int below = __popcll(msk & ((1ull << s) - 1ull));
    float dep = fmaf(f, (float)s * DELTA, nr);
    float sx = fmaf(dx, dep, ox) * invR;
    float sy = fmaf(dy, dep, oy) * invR;
    float sz = fmaf(dz, dep, oz) * invR;
    float prev = fmaf(f, (float)(s - 1) * DELTA, nr);
    float del = s ? (dep - prev) : 0.0f;
    int i1 = bit ? (idxvB + below) : (idxtB + (s - below));
    int b0 = (bit ? sv : st) + i1;
    buf[b0] = fridx;                   // ridx      (slot 0)
    buf[b0 + LQ] = dep;                // depth     (slot 1)
    buf[b0 + 2 * LQ] = del;            // deltas    (slot 2)
    buf[b0 + 3 * LQ] = (bit && below == 0) ? 1.0f : 0.0f;  // boundary (slot 3)
    int b1 = SB + (bit ? svS : stS) + 3 * i1;
    buf[b1] = sx; buf[b1 + 1] = sy; buf[b1 + 2] = sz;
  }
  __syncthreads();

  // ---- streaming write phase ----
  size_t M = (size_t)N * S;
  // global bases of the 4 scalar arrays: ridx 0, depth 4M, deltas 5M, bnd 6M
  const size_t A1 = 4 * M, A2 = 5 * M, A3 = 6 * M;

  // fused scalar runs (valid then tail)
  {
    int a0 = (-V0) & 3; if (a0 > cV) a0 = cV;
    int body = cV - a0, n4 = body >> 2, rem = body & 3;
    int l0 = sv + a0;                  // multiple of 4
    size_t g = (size_t)V0 + a0;
    for (int c = tid; c < n4; c += THREADS) {
      int l = l0 + 4 * c; size_t gg = g + 4 * (size_t)c;
      *(float4*)(out + gg)      = *(const float4*)&buf[l];
      *(float4*)(out + A1 + gg) = *(const float4*)&buf[l + LQ];
      *(float4*)(out + A2 + gg) = *(const float4*)&buf[l + 2 * LQ];
      *(float4*)(out + A3 + gg) = *(const float4*)&buf[l + 3 * LQ];
    }
    if (tid < a0) {
      size_t gg = (size_t)V0 + tid; int l = sv + tid;
      out[gg] = buf[l]; out[A1 + gg] = buf[l + LQ];
      out[A2 + gg] = buf[l + 2 * LQ]; out[A3 + gg] = buf[l + 3 * LQ];
    }
    if (tid < rem) {
      int e = a0 + 4 * n4 + tid;
      size_t gg = (size_t)V0 + e; int l = sv + e;
      out[gg] = buf[l]; out[A1 + gg] = buf[l + LQ];
      out[A2 + gg] = buf[l + 2 * LQ]; out[A3 + gg] = buf[l + 3 * LQ];
    }
  }
  {
    int a0 = (int)((-tail0) & 3); if (a0 > cT) a0 = cT;
    int body = cT - a0, n4 = body >> 2, rem = body & 3;
    int l0 = st + a0;
    size_t g = tail0 + a0;
    for (int c = tid; c < n4; c += THREADS) {
      int l = l0 + 4 * c; size_t gg = g + 4 * (size_t)c;
      *(float4*)(out + gg)      = *(const float4*)&buf[l];
      *(float4*)(out + A1 + gg) = *(const float4*)&buf[l + LQ];
      *(float4*)(out + A2 + gg) = *(const float4*)&buf[l + 2 * LQ];
      *(float4*)(out + A3 + gg) = *(const float4*)&buf[l + 3 * LQ];
    }
    if (tid < a0) {
      size_t gg = tail0 + tid; int l = st + tid;
      out[gg] = buf[l]; out[A1 + gg] = buf[l + LQ];
      out[A2 + gg] = buf[l + 2 * LQ]; out[A3 + gg] = buf[l + 3 * LQ];
    }
    if (tid < rem) {
      int e = a0 + 4 * n4 + tid;
      size_t gg = tail0 + e; int l = st + e;
      out[gg] = buf[l]; out[A1 + gg] = buf[l + LQ];
      out[A2 + gg] = buf[l + 2 * LQ]; out[A3 + gg] = buf[l + 3 * LQ];
    }
  }
  // samples runs (scale 3)
  {
    size_t g0 = M + 3 * (size_t)V0; int cnt = 3 * cV;
    int a0 = (int)((-g0) & 3); if (a0 > cnt) a0 = cnt;
    int body = cnt - a0, n4 = body >> 2, rem = body & 3;
    int l0 = SB + svS + a0;
    for (int c = tid; c < n4; c += THREADS)
      *(float4*)(out + g0 + a0 + 4 * (size_t)c) = *(const float4*)&buf[l0 + 4 * c];
    if (tid < a0) out[g0 + tid] = buf[SB + svS + tid];
    if (tid < rem) { int e = a0 + 4 * n4 + tid; out[g0 + e] = buf[SB + svS + e]; }
  }
  {
    size_t g0 = M + 3 * tail0; int cnt = 3 * cT;
    int a0 = (int)((-g0) & 3); if (a0 > cnt) a0 = cnt;
    int body = cnt - a0, n4 = body >> 2, rem = body & 3;
    int l0 = SB + stS + a0;
    for (int c = tid; c < n4; c += THREADS)
      *(float4*)(out + g0 + a0 + 4 * (size_t)c) = *(const float4*)&buf[l0 + 4 * c];
    if (tid < a0) out[g0 + tid] = buf[SB + stS + tid];
    if (tid < rem) { int e = a0 + 4 * n4 + tid; out[g0 + e] = buf[SB + stS + e]; }
  }
}

}  // namespace

extern "C" void kernel_launch(void* const* d_in, const int* in_sizes, int n_in,
                              void* d_out, int out_size, void* d_ws, size_t ws_size,
                              hipStream_t stream) {
  const float* ro = (const float*)d_in[0];
  const float* rd = (const float*)d_in[1];
  const float* radii = (const float*)d_in[2];
  int N = in_sizes[0] / 3;           // 262144
  int M = N * S;                     // 16777216
  int nbA = (N + 255) / 256;         // 1024

  float4* rayinfo = (float4*)d_ws;             // N float4 (16B aligned)
  int* wsI = (int*)(rayinfo + N);
  int* L = wsI;                      // N ints
  int* blockSums = wsI + N;          // nbA ints
  int* blockOff = blockSums + nbA;   // nbA ints
  int* total = blockOff + nbA;       // 1 int

  float* out = (float*)d_out;
  float* out_nv = out + (size_t)7 * (size_t)M;  // num_valid slot

  k_count<<<nbA, 256, 0, stream>>>(ro, rd, radii, rayinfo, L, blockSums, N);
  k_scan<<<1, 1024, 0, stream>>>(blockSums, blockOff, total, out_nv, nbA);
  k_stage<<<N / RPB, THREADS, 0, stream>>>(ro, rd, radii, rayinfo, L, blockOff,
                                           total, out, N);
}